// Round 9
// baseline (183.045 us; speedup 1.0000x reference)
//
#include <hip/hip_runtime.h>
#include <math.h>

#define BATCH 256
#define DIN   5120
#define RANK  160
#define NS    16
#define NCAT  192   // RANK + NS + NS
#define NSPLIT 40   // k-splits for k1

// ---------------------------------------------------------------------------
// k1a: partial[z] = x(256x5120) @ [W_delta | W_B | W_C] over k-chunk z.
// Split-K (40 chunks of 128), 64x64 tile, 4x4 reg tile. NO atomics.
// ---------------------------------------------------------------------------
__global__ __launch_bounds__(256) void k1a_gemm(
    const float* __restrict__ x, const float* __restrict__ Wd,
    const float* __restrict__ WB, const float* __restrict__ WC,
    float* __restrict__ psum)
{
    __shared__ float xT[32][64];   // [k][m]
    __shared__ float Wt[32][64];   // [k][n]
    const int t  = threadIdx.x;
    const int m0 = blockIdx.x * 64;
    const int n0 = blockIdx.y * 64;
    const int z  = blockIdx.z;
    const int k0 = z * 128;
    const int tm = (t >> 4) * 4;
    const int tn = (t & 15) * 4;

    const int lm  = t >> 2;
    const int lk  = (t & 3) * 8;
    const int ln  = t & 63;
    const int lkb = (t >> 6) * 8;

    const float* wsrc; int wstr;
    {
        const int c = n0 + ln;
        if (c < RANK)            { wsrc = Wd + c;                wstr = RANK; }
        else if (c < RANK + NS)  { wsrc = WB + (c - RANK);       wstr = NS;   }
        else                     { wsrc = WC + (c - RANK - NS);  wstr = NS;   }
    }

    float acc[4][4] = {{0.f}};

    for (int ks = 0; ks < 4; ++ks) {
        const int kb = k0 + ks * 32;
        {
            const float* src = x + (size_t)(m0 + lm) * DIN + kb + lk;
            const float4 a0 = *(const float4*)src;
            const float4 a1 = *(const float4*)(src + 4);
            xT[lk+0][lm]=a0.x; xT[lk+1][lm]=a0.y; xT[lk+2][lm]=a0.z; xT[lk+3][lm]=a0.w;
            xT[lk+4][lm]=a1.x; xT[lk+5][lm]=a1.y; xT[lk+6][lm]=a1.z; xT[lk+7][lm]=a1.w;
        }
        {
            const float* wp = wsrc + (size_t)(kb + lkb) * wstr;
            #pragma unroll
            for (int i = 0; i < 8; ++i) { Wt[lkb + i][ln] = *wp; wp += wstr; }
        }
        __syncthreads();
        #pragma unroll
        for (int k = 0; k < 32; ++k) {
            const float4 a = *(const float4*)&xT[k][tm];
            const float4 b = *(const float4*)&Wt[k][tn];
            acc[0][0] += a.x*b.x; acc[0][1] += a.x*b.y; acc[0][2] += a.x*b.z; acc[0][3] += a.x*b.w;
            acc[1][0] += a.y*b.x; acc[1][1] += a.y*b.y; acc[1][2] += a.y*b.z; acc[1][3] += a.y*b.w;
            acc[2][0] += a.z*b.x; acc[2][1] += a.z*b.y; acc[2][2] += a.z*b.z; acc[2][3] += a.z*b.w;
            acc[3][0] += a.w*b.x; acc[3][1] += a.w*b.y; acc[3][2] += a.w*b.z; acc[3][3] += a.w*b.w;
        }
        __syncthreads();
    }

    float* dst = psum + (size_t)z * (BATCH * NCAT);
    #pragma unroll
    for (int i = 0; i < 4; ++i) {
        const int gm = m0 + tm + i;
        float4 o; o.x = acc[i][0]; o.y = acc[i][1]; o.z = acc[i][2]; o.w = acc[i][3];
        *(float4*)&dst[(size_t)gm * NCAT + n0 + tn] = o;
    }
}

// ---------------------------------------------------------------------------
// k1r: (blocks 0..191) reduce 40 psum partials -> P/Bp/Cc;
//      (all 320 blocks) A2 = -log2(e)*exp(A_log), 81920 elements.
// ---------------------------------------------------------------------------
__global__ __launch_bounds__(256) void k1r_reduce(
    const float* __restrict__ psum, const float* __restrict__ A_log,
    float* __restrict__ P, float* __restrict__ Bp, float* __restrict__ Cc,
    float* __restrict__ A2t)
{
    const int g = blockIdx.x * 256 + threadIdx.x;     // 0..81919
    A2t[g] = -1.442695041f * __expf(A_log[g]);

    if (blockIdx.x < NCAT) {
        const int o = blockIdx.x * 256 + threadIdx.x; // 0..49151
        float s = 0.f;
        #pragma unroll 8
        for (int z = 0; z < NSPLIT; ++z) s += psum[(size_t)z * (BATCH * NCAT) + o];
        const int gm = o / NCAT;
        const int gc = o - gm * NCAT;
        if (gc < RANK)           P [gm * RANK + gc]             = s;
        else if (gc < RANK + NS) Bp[gm * NS   + gc - RANK]      = s;
        else                     Cc[gm * NS   + gc - RANK - NS] = s;
    }
}

__device__ __forceinline__ float softplus20(float z)
{
    if (z > 20.f) return z;
    return fmaxf(z, 0.f) + log1pf(__expf(-fabsf(z)));
}

// ---------------------------------------------------------------------------
// k2a: dt(256x5120) = softplus(P(256x160) @ W_dt(160x5120) + b_dt)
// 64x64 LDS tile, K=160 in 5 stages of 32, fused bias+softplus. grid (4,80).
// Proven structure (R4/R6); dtb round-trip (10 MB) is cheaper than the
// occupancy loss of fusing with the SSM pass (R8: 11% occ, 55 us).
// ---------------------------------------------------------------------------
__global__ __launch_bounds__(256) void k2a_gemm(
    const float* __restrict__ P, const float* __restrict__ Wdt,
    const float* __restrict__ bdt, float* __restrict__ dtb)
{
    __shared__ float aT[32][64];
    __shared__ float Bt[32][64];
    const int t  = threadIdx.x;
    const int m0 = blockIdx.x * 64;
    const int n0 = blockIdx.y * 64;
    const int tm = (t >> 4) * 4;
    const int tn = (t & 15) * 4;

    const int lm  = t >> 2;
    const int lk  = (t & 3) * 8;
    const int ln  = t & 63;
    const int lkb = (t >> 6) * 8;

    float acc[4][4] = {{0.f}};

    for (int ks = 0; ks < 5; ++ks) {
        const int kb = ks * 32;
        {
            const float* src = P + (size_t)(m0 + lm) * RANK + kb + lk;
            const float4 a0 = *(const float4*)src;
            const float4 a1 = *(const float4*)(src + 4);
            aT[lk+0][lm]=a0.x; aT[lk+1][lm]=a0.y; aT[lk+2][lm]=a0.z; aT[lk+3][lm]=a0.w;
            aT[lk+4][lm]=a1.x; aT[lk+5][lm]=a1.y; aT[lk+6][lm]=a1.z; aT[lk+7][lm]=a1.w;
        }
        {
            const float* wp = Wdt + (size_t)(kb + lkb) * DIN + n0 + ln;
            #pragma unroll
            for (int i = 0; i < 8; ++i) { Bt[lkb + i][ln] = wp[(size_t)i * DIN]; }
        }
        __syncthreads();
        #pragma unroll
        for (int k = 0; k < 32; ++k) {
            const float4 a = *(const float4*)&aT[k][tm];
            const float4 b = *(const float4*)&Bt[k][tn];
            acc[0][0] += a.x*b.x; acc[0][1] += a.x*b.y; acc[0][2] += a.x*b.z; acc[0][3] += a.x*b.w;
            acc[1][0] += a.y*b.x; acc[1][1] += a.y*b.y; acc[1][2] += a.y*b.z; acc[1][3] += a.y*b.w;
            acc[2][0] += a.z*b.x; acc[2][1] += a.z*b.y; acc[2][2] += a.z*b.z; acc[2][3] += a.z*b.w;
            acc[3][0] += a.w*b.x; acc[3][1] += a.w*b.y; acc[3][2] += a.w*b.z; acc[3][3] += a.w*b.w;
        }
        __syncthreads();
    }

    const float4 bz = *(const float4*)&bdt[n0 + tn];
    #pragma unroll
    for (int i = 0; i < 4; ++i) {
        const int gm = m0 + tm + i;
        float4 o;
        o.x = softplus20(acc[i][0] + bz.x);
        o.y = softplus20(acc[i][1] + bz.y);
        o.z = softplus20(acc[i][2] + bz.z);
        o.w = softplus20(acc[i][3] + bz.w);
        *(float4*)&dtb[(size_t)gm * DIN + n0 + tn] = o;
    }
}

// ---------------------------------------------------------------------------
// k3: SSM update + readout, grid (20, 256) = 5120 blocks -> max occupancy
// (wave-limited, 8 blocks/CU). Block = 1 batch x 256 channels, 4 waves.
// Lane 4j+v of instruction q: channel c = c0 + wv*64 + q*16 + j, states
// 4v..4v+3 -> every h/A2t wave-load is 1 KB contiguous. 4-lane shfl_xor
// finishes the n-sum; lanes v==0 store 16 consecutive y floats.
// ---------------------------------------------------------------------------
__global__ __launch_bounds__(256) void k3_ssm(
    const float* __restrict__ dtb, const float* __restrict__ x,
    const float* __restrict__ h, const float* __restrict__ A2t,
    const float* __restrict__ Bp, const float* __restrict__ Cc,
    const float* __restrict__ Dv, float* __restrict__ y)
{
    const int t    = threadIdx.x;
    const int lane = t & 63;
    const int wv   = t >> 6;
    const int b    = blockIdx.y;
    const int cb   = blockIdx.x * 256 + wv * 64;   // 64 channels per wave

    const int v = lane & 3;    // state quad: n = 4v..4v+3
    const int j = lane >> 2;   // channel within 16

    const float4 B4 = *(const float4*)(Bp + b * NS + v * 4);
    const float4 C4 = *(const float4*)(Cc + b * NS + v * 4);

    float res[4];
    #pragma unroll
    for (int q = 0; q < 4; ++q) {
        const int c = cb + q * 16 + j;
        const float dtv = dtb[(size_t)b * DIN + c];
        const float xv  = x  [(size_t)b * DIN + c];
        const float dtx = dtv * xv;
        const float4 h4 = *(const float4*)(h   + ((size_t)b * DIN + c) * NS + v * 4);
        const float4 a4 = *(const float4*)(A2t + (size_t)c * NS + v * 4);
        float s;
        s  = (exp2f(dtv * a4.x) * h4.x + dtx * B4.x) * C4.x;
        s += (exp2f(dtv * a4.y) * h4.y + dtx * B4.y) * C4.y;
        s += (exp2f(dtv * a4.z) * h4.z + dtx * B4.z) * C4.z;
        s += (exp2f(dtv * a4.w) * h4.w + dtx * B4.w) * C4.w;
        if (v == 0) s += xv * Dv[c];
        res[q] = s;
    }

    #pragma unroll
    for (int q = 0; q < 4; ++q) {
        res[q] += __shfl_xor(res[q], 1, 64);
        res[q] += __shfl_xor(res[q], 2, 64);
    }
    if (v == 0) {
        #pragma unroll
        for (int q = 0; q < 4; ++q)
            y[(size_t)b * DIN + cb + q * 16 + j] = res[q];
    }
}

// ---------------------------------------------------------------------------
extern "C" void kernel_launch(void* const* d_in, const int* in_sizes, int n_in,
                              void* d_out, int out_size, void* d_ws, size_t ws_size,
                              hipStream_t stream)
{
    const float* x     = (const float*)d_in[0];
    const float* h     = (const float*)d_in[1];
    const float* Wd    = (const float*)d_in[2];
    const float* Wdt   = (const float*)d_in[3];
    const float* bdt   = (const float*)d_in[4];
    const float* A_log = (const float*)d_in[5];
    const float* WB    = (const float*)d_in[6];
    const float* WC    = (const float*)d_in[7];
    const float* Dv    = (const float*)d_in[8];
    float* out = (float*)d_out;

    // ws layout (floats): psum (40x256x192) | P | Bp | Cc | A2 (5120x16) | dtb
    float* psum = (float*)d_ws;
    float* P    = psum + (size_t)NSPLIT * BATCH * NCAT;
    float* Bp   = P  + BATCH * RANK;
    float* Cc   = Bp + BATCH * NS;
    float* A2t  = Cc + BATCH * NS;
    float* dtb  = A2t + (size_t)DIN * NS;

    // no memset needed: every ws word is written before it is read
    k1a_gemm  <<<dim3(4, 3, NSPLIT), 256, 0, stream>>>(x, Wd, WB, WC, psum);
    k1r_reduce<<<dim3(320),          256, 0, stream>>>(psum, A_log, P, Bp, Cc, A2t);
    k2a_gemm  <<<dim3(4, 80),        256, 0, stream>>>(P, Wdt, bdt, dtb);
    k3_ssm    <<<dim3(20, BATCH),    256, 0, stream>>>(dtb, x, h, A2t, Bp, Cc, Dv, out);
}